// Round 1
// baseline (178.141 us; speedup 1.0000x reference)
//
#include <hip/hip_runtime.h>
#include <stdint.h>

#define MTOK 16384
#define KD 256
#define NO 256
#define NE 16
#define BM 64
#define BN 128
#define BK 32
#define XROW 264   // bf16 elems per Xs row: 256 + 8 pad (bank-balance, keeps 16B align)
#define WROW 40    // bf16 elems per Ws row: 32 + 8 pad
#define NCHUNK 128 // (KD/BK) * NE

typedef short bf16x8 __attribute__((ext_vector_type(8)));
typedef float f32x4 __attribute__((ext_vector_type(4)));

__device__ __forceinline__ unsigned short f2bf(float f) {
  uint32_t u = __float_as_uint(f);
  u += 0x7fffu + ((u >> 16) & 1u);   // RNE (inputs are finite)
  return (unsigned short)(u >> 16);
}
__device__ __forceinline__ float bf2f(unsigned short h) {
  return __uint_as_float(((uint32_t)h) << 16);
}
// gelu(h) = h * sigmoid(1.59576912 h + 0.07135482 h^3)  (tanh approximation)
__device__ __forceinline__ float gelu_f(float h) {
  float z = h * fmaf(0.07135481627f, h * h, 1.5957691216f);
  return h * __builtin_amdgcn_rcpf(1.0f + __expf(-z));
}

// ---------------- prep: We transpose->bf16  +  gate softmax ----------------
__global__ void moe_prep(const float* __restrict__ We, unsigned short* __restrict__ Wt,
                         const float* __restrict__ x, const float* __restrict__ Wg,
                         const float* __restrict__ bg, float* __restrict__ gate)
{
  __shared__ float smem[12544];  // 50176 B; transpose uses 4160, gate uses 12544
  const int tid = threadIdx.x;
  const int bid = blockIdx.x;
  if (bid < 256) {
    // transpose We[e][d][o] -> Wt[e][o][d], fp32 -> bf16; 64x64 tile per block
    int e = bid >> 4;
    int d0 = ((bid >> 2) & 3) * 64;
    int o0 = (bid & 3) * 64;
    float* ts = smem;                       // [64][65]
    int c = tid & 63, rg = tid >> 6;
    const float* src = We + ((size_t)e * KD + d0) * NO + o0;
#pragma unroll
    for (int i = 0; i < 16; ++i) {
      int r = i * 4 + rg;                   // d-local
      ts[c * 65 + r] = src[r * NO + c];     // ts[o][d]
    }
    __syncthreads();
    unsigned short* dst = Wt + ((size_t)e * NO + o0) * KD + d0;
#pragma unroll
    for (int i = 0; i < 16; ++i) {
      int o = i * 4 + rg;
      dst[o * KD + c] = f2bf(ts[o * 65 + c]);
    }
  } else {
    // gate: 1 thread = 1 token; 4 waves x 64 tokens per block
    int gb = bid - 256;                     // 0..63
    float* wg_s = smem;                     // 4096 floats = Wg[256][16]
    float* xs = smem + 4096;                // 4 x [64][33]
#pragma unroll
    for (int i = 0; i < 16; ++i) wg_s[i * 256 + tid] = Wg[i * 256 + tid];
    __syncthreads();
    int w = tid >> 6, l = tid & 63;
    int tbase = gb * 256 + w * 64;
    const float* xrow0 = x + (size_t)tbase * KD;
    float* xw = xs + w * (64 * 33);
    float acc[NE];
#pragma unroll
    for (int e = 0; e < NE; ++e) acc[e] = 0.f;
    for (int dc = 0; dc < 8; ++dc) {
      // stage x chunk [64 tokens][32 d] (coalesced; per-wave region, in-order wave => no barrier)
#pragma unroll
      for (int i = 0; i < 32; ++i) {
        int idx = i * 64 + l;
        int r = idx >> 5, cc = idx & 31;
        xw[r * 33 + cc] = xrow0[(size_t)r * KD + dc * 32 + cc];
      }
#pragma unroll
      for (int d = 0; d < 32; ++d) {
        float xv = xw[l * 33 + d];
        const float* wr = &wg_s[(dc * 32 + d) * NE];
#pragma unroll
        for (int e = 0; e < NE; ++e) acc[e] = fmaf(xv, wr[e], acc[e]);
      }
    }
    float mx = -1e30f;
#pragma unroll
    for (int e = 0; e < NE; ++e) { acc[e] += bg[e]; mx = fmaxf(mx, acc[e]); }
    float s = 0.f;
#pragma unroll
    for (int e = 0; e < NE; ++e) { acc[e] = __expf(acc[e] - mx); s += acc[e]; }
    float inv = __builtin_amdgcn_rcpf(s);
    float4* gout = (float4*)(gate + (size_t)(tbase + l) * NE);
#pragma unroll
    for (int q = 0; q < 4; ++q)
      gout[q] = make_float4(acc[q*4+0]*inv, acc[q*4+1]*inv, acc[q*4+2]*inv, acc[q*4+3]*inv);
  }
}

// ---------------- main: X-tile-resident MFMA GEMM over all experts, fused epilogue ----------------
__launch_bounds__(256, 2)
__global__ void moe_main(const float* __restrict__ x,
                         const unsigned short* __restrict__ Wt,
                         const float* __restrict__ be,
                         const float* __restrict__ gate,
                         float* __restrict__ out)
{
  __shared__ unsigned short Xs[BM * XROW];      // 33792 B, resident across all experts
  __shared__ unsigned short Ws[2][BN * WROW];   // 2 x 10240 B, double-buffered W k-chunks
  __shared__ float gate_t[NE * BM];             // 4096 B, gate transposed [e][row]
  __shared__ unsigned short be_h[NE * BN];      // 4096 B  (|be|<=1/16 -> bf16 err ~1e-4)
  // total 62464 B -> 2 blocks/CU

  const int tid = threadIdx.x;
  const int bid = blockIdx.x;
  const int n0 = (bid & 1) * BN;
  const int m0 = (bid >> 1) * BM;
  const int wid = tid >> 6;
  const int lane = tid & 63;
  const int wm = wid >> 1, wn = wid & 1;        // 2x2 wave grid, wave tile 32x64
  const int ln = lane & 15, quad = lane >> 4;

  // ---- stage X tile: 64 rows x 256 fp32 -> bf16 (coalesced float4 loads)
  {
    const float4* xg = (const float4*)x + (size_t)m0 * (KD / 4);
#pragma unroll
    for (int p = 0; p < 16; ++p) {
      int idx = p * 256 + tid;
      int r = idx >> 6, c = idx & 63;
      float4 v = xg[r * (KD / 4) + c];
      uint32_t lo = (uint32_t)f2bf(v.x) | ((uint32_t)f2bf(v.y) << 16);
      uint32_t hi = (uint32_t)f2bf(v.z) | ((uint32_t)f2bf(v.w) << 16);
      *(uint2*)&Xs[r * XROW + c * 4] = make_uint2(lo, hi);
    }
  }
  // ---- stage gate (transposed) and bias
#pragma unroll
  for (int p = 0; p < 4; ++p) {
    int idx = p * 256 + tid;
    int r = idx >> 4, e = idx & 15;
    gate_t[e * BM + r] = gate[(size_t)(m0 + r) * NE + e];
  }
#pragma unroll
  for (int p = 0; p < 8; ++p) {
    int idx = p * 256 + tid;
    int e = idx >> 7, cc = idx & 127;
    be_h[e * BN + cc] = f2bf(be[e * NO + n0 + cc]);
  }

  // W chunk prefetch: chunk t = e*8 + kc; 512 16B pieces, 2 per thread
  const int pj = tid & 3;
  auto gsrcW = [&](int t, int pp) -> const uint4* {
    int e = t >> 3, kc = t & 7;
    int row = pp * 64 + (tid >> 2);
    return (const uint4*)(Wt + (((size_t)e * NO + n0 + row) * KD + kc * BK + pj * 8));
  };
  uint4 wpre0 = *gsrcW(0, 0), wpre1 = *gsrcW(0, 1);
  *(uint4*)&Ws[0][(tid >> 2) * WROW + pj * 8] = wpre0;
  *(uint4*)&Ws[0][(64 + (tid >> 2)) * WROW + pj * 8] = wpre1;
  __syncthreads();

  f32x4 acc[2][4], oacc[2][4];
#pragma unroll
  for (int i = 0; i < 2; ++i)
#pragma unroll
    for (int j = 0; j < 4; ++j) {
      acc[i][j] = (f32x4){0.f, 0.f, 0.f, 0.f};
      oacc[i][j] = (f32x4){0.f, 0.f, 0.f, 0.f};
    }

  const int arow0 = wm * 32 + ln;   // + i*16
  const int brow0 = wn * 64 + ln;   // + j*16

  for (int t = 0; t < NCHUNK; ++t) {
    const int e = t >> 3, kc = t & 7;
    const unsigned short* wbuf = Ws[t & 1];
    if (t < NCHUNK - 1) { wpre0 = *gsrcW(t + 1, 0); wpre1 = *gsrcW(t + 1, 1); }

    bf16x8 a[2], b[4];
    const int ka = kc * BK + quad * 8;
#pragma unroll
    for (int i = 0; i < 2; ++i)
      a[i] = *(const bf16x8*)&Xs[(arow0 + i * 16) * XROW + ka];
    const int kb = quad * 8;
#pragma unroll
    for (int j = 0; j < 4; ++j)
      b[j] = *(const bf16x8*)&wbuf[(brow0 + j * 16) * WROW + kb];
#pragma unroll
    for (int i = 0; i < 2; ++i)
#pragma unroll
      for (int j = 0; j < 4; ++j)
        acc[i][j] = __builtin_amdgcn_mfma_f32_16x16x32_bf16(a[i], b[j], acc[i][j], 0, 0, 0);

    if (kc == 7) {  // expert finished: bias + gelu + gate-weighted accumulate
#pragma unroll
      for (int j = 0; j < 4; ++j) {
        float bias = bf2f(be_h[e * BN + brow0 + j * 16]);
#pragma unroll
        for (int i = 0; i < 2; ++i) {
#pragma unroll
          for (int r = 0; r < 4; ++r) {
            int row = wm * 32 + i * 16 + quad * 4 + r;   // C layout: col=ln, row=quad*4+r
            float g = gate_t[e * BM + row];
            float h = acc[i][j][r] + bias;
            oacc[i][j][r] = fmaf(g, gelu_f(h), oacc[i][j][r]);
            acc[i][j][r] = 0.f;
          }
        }
      }
    }
    // write next chunk into other buffer (its last readers finished before prev barrier)
    if (t < NCHUNK - 1) {
      int buf = (t + 1) & 1;
      *(uint4*)&Ws[buf][(tid >> 2) * WROW + pj * 8] = wpre0;
      *(uint4*)&Ws[buf][(64 + (tid >> 2)) * WROW + pj * 8] = wpre1;
    }
    __syncthreads();
  }

  // ---- store (each out element owned by exactly one block)
#pragma unroll
  for (int i = 0; i < 2; ++i)
#pragma unroll
    for (int r = 0; r < 4; ++r) {
      int row = m0 + wm * 32 + i * 16 + quad * 4 + r;
      float* orow = out + (size_t)row * NO + n0 + wn * 64 + ln;
      orow[0]  = oacc[i][0][r];
      orow[16] = oacc[i][1][r];
      orow[32] = oacc[i][2][r];
      orow[48] = oacc[i][3][r];
    }
}

extern "C" void kernel_launch(void* const* d_in, const int* in_sizes, int n_in,
                              void* d_out, int out_size, void* d_ws, size_t ws_size,
                              hipStream_t stream) {
  const float* x  = (const float*)d_in[0];
  const float* We = (const float*)d_in[1];
  const float* be = (const float*)d_in[2];
  const float* Wg = (const float*)d_in[3];
  const float* bg = (const float*)d_in[4];
  float* out = (float*)d_out;
  unsigned short* Wt = (unsigned short*)d_ws;                       // 2 MB bf16 [E][O][D]
  float* gate = (float*)((char*)d_ws + (size_t)NE * NO * KD * 2);   // 1 MB fp32 [M][E]

  moe_prep<<<320, 256, 0, stream>>>(We, Wt, x, Wg, bg, gate);
  moe_main<<<512, 256, 0, stream>>>(x, Wt, be, gate, out);
}

// Round 2
// 131.902 us; speedup vs baseline: 1.3506x; 1.3506x over previous
//
#include <hip/hip_runtime.h>
#include <stdint.h>

#define KD 256
#define NO 256
#define NE 16
#define BM 64
#define BN 128
#define BKK 64          // k per LDS W chunk
#define WROW 72         // 64 + 8 pad (shorts) -> 144 B row stride
#define XROW 264        // X stage row stride (shorts)
#define NIT 64          // NE * (KD/BKK)

typedef short bf16x8 __attribute__((ext_vector_type(8)));
typedef float f32x4 __attribute__((ext_vector_type(4)));

__device__ __forceinline__ unsigned short f2bf(float f) {
  uint32_t u = __float_as_uint(f);
  u += 0x7fffu + ((u >> 16) & 1u);   // RNE (finite inputs)
  return (unsigned short)(u >> 16);
}
__device__ __forceinline__ float bf2f(unsigned short h) {
  return __uint_as_float(((uint32_t)h) << 16);
}
// gelu(h) = h * sigmoid(1.59576912 h + 0.07135482 h^3)  (tanh form)
__device__ __forceinline__ float gelu_f(float h) {
  float z = h * fmaf(0.07135481627f, h * h, 1.5957691216f);
  return h * __builtin_amdgcn_rcpf(1.0f + __expf(-z));
}

// ---------------- prep: We transpose->bf16, Wg transpose->bf16 ----------------
__global__ void moe_prep(const float* __restrict__ We, unsigned short* __restrict__ Wt,
                         const float* __restrict__ Wg, unsigned short* __restrict__ Wgt)
{
  __shared__ float ts[64 * 65];
  const int tid = threadIdx.x;
  const int bid = blockIdx.x;
  if (bid < 256) {
    // We[e][d][o] -> Wt[e][o][d] bf16; 64x64 tile per block
    int e = bid >> 4;
    int d0 = ((bid >> 2) & 3) * 64;
    int o0 = (bid & 3) * 64;
    int c = tid & 63, rg = tid >> 6;
    const float* src = We + ((size_t)e * KD + d0) * NO + o0;
#pragma unroll
    for (int i = 0; i < 16; ++i) {
      int r = i * 4 + rg;
      ts[c * 65 + r] = src[r * NO + c];
    }
    __syncthreads();
    unsigned short* dst = Wt + ((size_t)e * NO + o0) * KD + d0;
#pragma unroll
    for (int i = 0; i < 16; ++i) {
      int o = i * 4 + rg;
      dst[o * KD + c] = f2bf(ts[o * 65 + c]);
    }
  } else {
    // Wg[d][e] -> Wgt[e][d] bf16
    int d = tid;
    const float* wr = Wg + (size_t)d * NE;
#pragma unroll
    for (int e = 0; e < NE; ++e)
      Wgt[e * KD + d] = f2bf(wr[e]);
  }
}

// ---------------- main: A-in-regs MFMA GEMM + in-kernel gate + fused epilogue --------
__launch_bounds__(256, 2)
__global__ void moe_main(const float* __restrict__ x,
                         const unsigned short* __restrict__ Wt,
                         const unsigned short* __restrict__ Wgt,
                         const float* __restrict__ be,
                         const float* __restrict__ bg,
                         float* __restrict__ out)
{
  // union buffer: first X stage (64x264 = 16896 sh), then W dbuf (2 x 128x72 = 18432 sh)
  __shared__ __align__(16) unsigned short u_lds[2 * BN * WROW];  // 36864 B
  __shared__ float gate_t[NE * 65];                              // 4160 B
  __shared__ unsigned short be_h[NE * BN];                       // 4096 B

  const int tid = threadIdx.x;
  const int bid = blockIdx.x;
  const int n0 = (bid & 1) * BN;          // bid,bid+256 share n-half -> L1/L2 locality
  const int m0 = (bid >> 1) * BM;
  const int wid = tid >> 6, lane = tid & 63;
  const int wm = wid >> 1, wn = wid & 1;  // 2x2 wave grid, wave tile 32x64
  const int ln = lane & 15, quad = lane >> 4;

  // ---- W chunk staging geometry: 4 x 16B pieces per thread
  const int srow = tid >> 3;              // 0..31 (+32/64/96)
  const int spj = tid & 7;                // 16B piece within 128B k-row
  auto wgsrc = [&](int t, int pass) -> const uint4* {
    int e = t >> 2, kc = t & 3;
    int row = pass * 32 + srow;
    return (const uint4*)(Wt + (((size_t)e * NO + n0 + row) * KD + kc * BKK + spj * 8));
  };

  // issue chunk 0 global loads early
  uint4 w0 = *wgsrc(0, 0), w1 = *wgsrc(0, 1), w2 = *wgsrc(0, 2), w3 = *wgsrc(0, 3);

  // ---- stage X tile fp32 -> bf16 into union buffer
  {
    const float4* xg = (const float4*)x + (size_t)m0 * (KD / 4);
#pragma unroll
    for (int p = 0; p < 16; ++p) {
      int idx = p * 256 + tid;
      int r = idx >> 6, c = idx & 63;
      float4 v = xg[r * (KD / 4) + c];
      uint32_t lo = (uint32_t)f2bf(v.x) | ((uint32_t)f2bf(v.y) << 16);
      uint32_t hi = (uint32_t)f2bf(v.z) | ((uint32_t)f2bf(v.w) << 16);
      *(uint2*)&u_lds[r * XROW + c * 4] = make_uint2(lo, hi);
    }
  }
  // ---- stage bias (bf16; |be|<=1/16 so error ~1e-4)
#pragma unroll
  for (int p = 0; p < 8; ++p) {
    int idx = p * 256 + tid;
    int e = idx >> 7, c = idx & 127;
    be_h[e * BN + c] = f2bf(be[e * NO + n0 + c]);
  }
  __syncthreads();

  // ---- A fragments (full K) to registers: 16 frags = 64 VGPR
  bf16x8 a[2][8];
  const int arow = wm * 32 + ln;
#pragma unroll
  for (int i = 0; i < 2; ++i)
#pragma unroll
    for (int kc = 0; kc < 8; ++kc)
      a[i][kc] = *(const bf16x8*)&u_lds[(arow + i * 16) * XROW + kc * 32 + quad * 8];

  // ---- gate: logits = X . Wg  via MFMA (lane ln = expert), softmax over 16 lanes
  {
    f32x4 g0 = {0.f, 0.f, 0.f, 0.f}, g1 = {0.f, 0.f, 0.f, 0.f};
#pragma unroll
    for (int kc = 0; kc < 8; ++kc) {
      bf16x8 wb = *(const bf16x8*)(Wgt + (size_t)ln * KD + kc * 32 + quad * 8);
      g0 = __builtin_amdgcn_mfma_f32_16x16x32_bf16(a[0][kc], wb, g0, 0, 0, 0);
      g1 = __builtin_amdgcn_mfma_f32_16x16x32_bf16(a[1][kc], wb, g1, 0, 0, 0);
    }
    float bgl = bg[ln];
#pragma unroll
    for (int i = 0; i < 2; ++i)
#pragma unroll
      for (int r = 0; r < 4; ++r) {
        float v = (i == 0 ? g0[r] : g1[r]) + bgl;
        float mx = v;
#pragma unroll
        for (int msk = 1; msk < 16; msk <<= 1)
          mx = fmaxf(mx, __shfl_xor(mx, msk, 64));
        float ev = __expf(v - mx);
        float s = ev;
#pragma unroll
        for (int msk = 1; msk < 16; msk <<= 1)
          s += __shfl_xor(s, msk, 64);
        float gv = ev * __builtin_amdgcn_rcpf(s);
        if (wn == 0)
          gate_t[ln * 65 + wm * 32 + i * 16 + quad * 4 + r] = gv;
      }
  }
  __syncthreads();  // Xs dead; gate_t visible

  // ---- write chunk 0, prefetch chunk 1
  {
    unsigned short* d = u_lds;
    *(uint4*)&d[(srow +  0) * WROW + spj * 8] = w0;
    *(uint4*)&d[(srow + 32) * WROW + spj * 8] = w1;
    *(uint4*)&d[(srow + 64) * WROW + spj * 8] = w2;
    *(uint4*)&d[(srow + 96) * WROW + spj * 8] = w3;
  }
  w0 = *wgsrc(1, 0); w1 = *wgsrc(1, 1); w2 = *wgsrc(1, 2); w3 = *wgsrc(1, 3);
  __syncthreads();

  f32x4 acc[2][4], oacc[2][4];
#pragma unroll
  for (int i = 0; i < 2; ++i)
#pragma unroll
    for (int j = 0; j < 4; ++j) {
      acc[i][j] = (f32x4){0.f, 0.f, 0.f, 0.f};
      oacc[i][j] = (f32x4){0.f, 0.f, 0.f, 0.f};
    }

  const int brow = wn * 64 + ln;

#pragma unroll 1
  for (int e = 0; e < NE; ++e) {
#pragma unroll
    for (int c = 0; c < 4; ++c) {
      const int t = (e << 2) + c;
      const unsigned short* wb = u_lds + (t & 1) * (BN * WROW);
      // stage chunk t+1 (regs -> other buffer); its readers finished before prev barrier
      if (c < 3 || e < NE - 1) {
        unsigned short* d = u_lds + ((t + 1) & 1) * (BN * WROW);
        *(uint4*)&d[(srow +  0) * WROW + spj * 8] = w0;
        *(uint4*)&d[(srow + 32) * WROW + spj * 8] = w1;
        *(uint4*)&d[(srow + 64) * WROW + spj * 8] = w2;
        *(uint4*)&d[(srow + 96) * WROW + spj * 8] = w3;
      }
      // issue global loads for chunk t+2
      if (t < NIT - 2) {
        w0 = *wgsrc(t + 2, 0); w1 = *wgsrc(t + 2, 1);
        w2 = *wgsrc(t + 2, 2); w3 = *wgsrc(t + 2, 3);
      }
      // compute: 8 ds_read_b128 + 16 MFMA
#pragma unroll
      for (int ks = 0; ks < 2; ++ks) {
        bf16x8 b[4];
#pragma unroll
        for (int j = 0; j < 4; ++j)
          b[j] = *(const bf16x8*)&wb[(brow + j * 16) * WROW + ks * 32 + quad * 8];
        const int kc = c * 2 + ks;
#pragma unroll
        for (int i = 0; i < 2; ++i)
#pragma unroll
          for (int j = 0; j < 4; ++j)
            acc[i][j] = __builtin_amdgcn_mfma_f32_16x16x32_bf16(a[i][kc], b[j], acc[i][j], 0, 0, 0);
      }
      __syncthreads();
    }
    // ---- expert epilogue: bias + gelu + gate-weighted accumulate
    {
      float gv[2][4];
#pragma unroll
      for (int i = 0; i < 2; ++i)
#pragma unroll
        for (int r = 0; r < 4; ++r)
          gv[i][r] = gate_t[e * 65 + wm * 32 + i * 16 + quad * 4 + r];
#pragma unroll
      for (int j = 0; j < 4; ++j) {
        float bias = bf2f(be_h[e * BN + brow + j * 16]);
#pragma unroll
        for (int i = 0; i < 2; ++i)
#pragma unroll
          for (int r = 0; r < 4; ++r) {
            float h = acc[i][j][r] + bias;
            oacc[i][j][r] = fmaf(gv[i][r], gelu_f(h), oacc[i][j][r]);
            acc[i][j][r] = 0.f;
          }
      }
    }
  }

  // ---- store (each out element owned by exactly one block)
#pragma unroll
  for (int i = 0; i < 2; ++i)
#pragma unroll
    for (int r = 0; r < 4; ++r) {
      int row = m0 + wm * 32 + i * 16 + quad * 4 + r;
      float* orow = out + (size_t)row * NO + n0 + wn * 64 + ln;
      orow[0]  = oacc[i][0][r];
      orow[16] = oacc[i][1][r];
      orow[32] = oacc[i][2][r];
      orow[48] = oacc[i][3][r];
    }
}

extern "C" void kernel_launch(void* const* d_in, const int* in_sizes, int n_in,
                              void* d_out, int out_size, void* d_ws, size_t ws_size,
                              hipStream_t stream) {
  const float* x  = (const float*)d_in[0];
  const float* We = (const float*)d_in[1];
  const float* be = (const float*)d_in[2];
  const float* Wg = (const float*)d_in[3];
  const float* bg = (const float*)d_in[4];
  float* out = (float*)d_out;
  unsigned short* Wt  = (unsigned short*)d_ws;                        // 2 MB bf16 [E][O][D]
  unsigned short* Wgt = (unsigned short*)((char*)d_ws + (size_t)NE * NO * KD * 2);  // 8 KB bf16 [E][D]

  moe_prep<<<257, 256, 0, stream>>>(We, Wt, Wg, Wgt);
  moe_main<<<512, 256, 0, stream>>>(x, Wt, Wgt, be, bg, out);
}

// Round 3
// 127.709 us; speedup vs baseline: 1.3949x; 1.0328x over previous
//
#include <hip/hip_runtime.h>
#include <stdint.h>

#define KD 256
#define NO 256
#define NE 16
#define BM 64
#define BN 128
#define XROW 264        // X stage row stride (shorts): 256 + 8 pad
#define NFRAG 128       // NE * (KD/32) fragment-sets of K=32

typedef short bf16x8 __attribute__((ext_vector_type(8)));
typedef float f32x4 __attribute__((ext_vector_type(4)));

__device__ __forceinline__ unsigned short f2bf(float f) {
  uint32_t u = __float_as_uint(f);
  u += 0x7fffu + ((u >> 16) & 1u);   // RNE (finite inputs)
  return (unsigned short)(u >> 16);
}
__device__ __forceinline__ float bf2f(unsigned short h) {
  return __uint_as_float(((uint32_t)h) << 16);
}
// gelu(h) = h * sigmoid(1.59576912 h + 0.07135482 h^3)  (tanh form)
__device__ __forceinline__ float gelu_f(float h) {
  float z = h * fmaf(0.07135481627f, h * h, 1.5957691216f);
  return h * __builtin_amdgcn_rcpf(1.0f + __expf(-z));
}

// ---- prep: We[e][d][o] -> Wf fragment-ordered bf16; Wg[d][e] -> Wgt[e][d] bf16 ----
// Wf layout: [e][kc(0..7)][ob(0..15)][lane(0..63)][i(0..7)] bf16, where the stored
// element is We[e][ kc*32 + (lane>>4)*8 + i ][ ob*16 + (lane&15) ].
// One wave b-fragment load = 1 contiguous KB.
__global__ void moe_prep(const float* __restrict__ We, unsigned short* __restrict__ Wf,
                         const float* __restrict__ Wg, unsigned short* __restrict__ Wgt)
{
  __shared__ float ts[256 * 17];  // [d][o] tile, padded
  const int tid = threadIdx.x;
  const int bid = blockIdx.x;
  if (bid < 256) {
    const int e = bid >> 4, ob = bid & 15;
    const float* src = We + (size_t)e * KD * NO + ob * 16;
    const int o = tid & 15, dg = tid >> 4;
#pragma unroll
    for (int p = 0; p < 16; ++p) {
      int d = p * 16 + dg;
      ts[d * 17 + o] = src[(size_t)d * NO + o];
    }
    __syncthreads();
    const int w = tid >> 6, l = tid & 63;
    const int q = l >> 4, ln = l & 15;
#pragma unroll
    for (int kk = 0; kk < 2; ++kk) {
      int kc = w + kk * 4;
      unsigned int pk[4];
#pragma unroll
      for (int h = 0; h < 4; ++h) {
        unsigned short lo = f2bf(ts[(kc * 32 + q * 8 + h * 2 + 0) * 17 + ln]);
        unsigned short hi = f2bf(ts[(kc * 32 + q * 8 + h * 2 + 1) * 17 + ln]);
        pk[h] = (unsigned int)lo | ((unsigned int)hi << 16);
      }
      uint4* dst = (uint4*)(Wf + ((((size_t)(e * 8 + kc) * 16 + ob) * 64) + l) * 8);
      *dst = make_uint4(pk[0], pk[1], pk[2], pk[3]);
    }
  } else {
    // Wg[d][e] -> Wgt[e][d]
    int d = tid;
    const float* wr = Wg + (size_t)d * NE;
#pragma unroll
    for (int e = 0; e < NE; ++e)
      Wgt[e * KD + d] = f2bf(wr[e]);
  }
}

// ---- main: A-in-regs, B direct-from-global (fragment-ordered), no K-loop barriers ----
__launch_bounds__(256, 2)
__global__ void moe_main(const float* __restrict__ x,
                         const uint4* __restrict__ Wf,
                         const unsigned short* __restrict__ Wgt,
                         const float* __restrict__ be,
                         const float* __restrict__ bg,
                         float* __restrict__ out)
{
  __shared__ __align__(16) unsigned short Xs[BM * XROW];  // 33792 B
  __shared__ float gate_t[NE * 65];                        // 4160 B
  __shared__ unsigned short be_h[NE * BN];                 // 4096 B

  const int tid = threadIdx.x;
  const int bid = blockIdx.x;
  const int half = bid & 1;
  const int n0 = half * BN;
  const int m0 = (bid >> 1) * BM;
  const int wid = tid >> 6, lane = tid & 63;
  const int wm = wid >> 1, wn = wid & 1;   // 2x2 wave grid, wave tile 32x64
  const int ln = lane & 15, quad = lane >> 4;

  // per-wave constant fragment offset (uint4 units): frag j at +j*64
  const int voff = (half * 8 + wn * 4) * 64 + lane;

  // ---- stage X tile fp32 -> bf16
  {
    const float4* xg = (const float4*)x + (size_t)m0 * (KD / 4);
#pragma unroll
    for (int p = 0; p < 16; ++p) {
      int idx = p * 256 + tid;
      int r = idx >> 6, c = idx & 63;
      float4 v = xg[r * (KD / 4) + c];
      uint32_t lo = (uint32_t)f2bf(v.x) | ((uint32_t)f2bf(v.y) << 16);
      uint32_t hi = (uint32_t)f2bf(v.z) | ((uint32_t)f2bf(v.w) << 16);
      *(uint2*)&Xs[r * XROW + c * 4] = make_uint2(lo, hi);
    }
  }
  // ---- stage bias (bf16; |be|<=1/16 -> error ~1e-4)
#pragma unroll
  for (int p = 0; p < 8; ++p) {
    int idx = p * 256 + tid;
    int e = idx >> 7, c = idx & 127;
    be_h[e * BN + c] = f2bf(be[e * NO + n0 + c]);
  }
  __syncthreads();

  // ---- A fragments (full K) to registers: 16 frags = 64 VGPR
  bf16x8 a[2][8];
  const int arow = wm * 32 + ln;
#pragma unroll
  for (int i = 0; i < 2; ++i)
#pragma unroll
    for (int kc = 0; kc < 8; ++kc)
      a[i][kc] = *(const bf16x8*)&Xs[(arow + i * 16) * XROW + kc * 32 + quad * 8];

  // ---- preload first 4 fragment-sets (4-deep pipeline) while gate computes
  uint4 b[4][4];
#pragma unroll
  for (int t = 0; t < 4; ++t) {
    const uint4* p = Wf + (size_t)t * 1024 + voff;
    b[t][0] = p[0]; b[t][1] = p[64]; b[t][2] = p[128]; b[t][3] = p[192];
  }

  // ---- gate: logits = X . Wg via MFMA (lane ln = expert), softmax over 16 lanes
  {
    f32x4 g0 = {0.f, 0.f, 0.f, 0.f}, g1 = {0.f, 0.f, 0.f, 0.f};
#pragma unroll
    for (int kc = 0; kc < 8; ++kc) {
      bf16x8 wb = *(const bf16x8*)(Wgt + (size_t)ln * KD + kc * 32 + quad * 8);
      g0 = __builtin_amdgcn_mfma_f32_16x16x32_bf16(a[0][kc], wb, g0, 0, 0, 0);
      g1 = __builtin_amdgcn_mfma_f32_16x16x32_bf16(a[1][kc], wb, g1, 0, 0, 0);
    }
    float bgl = bg[ln];
#pragma unroll
    for (int i = 0; i < 2; ++i)
#pragma unroll
      for (int r = 0; r < 4; ++r) {
        float v = (i == 0 ? g0[r] : g1[r]) + bgl;
        float mx = v;
#pragma unroll
        for (int msk = 1; msk < 16; msk <<= 1)
          mx = fmaxf(mx, __shfl_xor(mx, msk, 64));
        float ev = __expf(v - mx);
        float s = ev;
#pragma unroll
        for (int msk = 1; msk < 16; msk <<= 1)
          s += __shfl_xor(s, msk, 64);
        float gv = ev * __builtin_amdgcn_rcpf(s);
        if (wn == 0)
          gate_t[ln * 65 + wm * 32 + i * 16 + quad * 4 + r] = gv;
      }
  }
  __syncthreads();  // gate_t visible; last barrier in the kernel

  f32x4 acc[2][4], oacc[2][4];
#pragma unroll
  for (int i = 0; i < 2; ++i)
#pragma unroll
    for (int j = 0; j < 4; ++j) {
      acc[i][j] = (f32x4){0.f, 0.f, 0.f, 0.f};
      oacc[i][j] = (f32x4){0.f, 0.f, 0.f, 0.f};
    }

  // ---- K-loop: barrier-free, 4-deep prefetch, buffer_load <-> MFMA interleave
#pragma unroll 1
  for (int e = 0; e < NE; ++e) {
#pragma unroll
    for (int h = 0; h < 4; ++h) {
      const int t = e * 8 + h * 2;
#pragma unroll
      for (int s = 0; s < 2; ++s) {        // two K=32 steps
        const int kc = h * 2 + s;
        uint4* bc = b[(t + s) & 3];
#pragma unroll
        for (int i = 0; i < 2; ++i)
#pragma unroll
          for (int j = 0; j < 4; ++j)
            acc[i][j] = __builtin_amdgcn_mfma_f32_16x16x32_bf16(
                a[i][kc], *(const bf16x8*)&bc[j], acc[i][j], 0, 0, 0);
        if (t + s + 4 < NFRAG) {           // refill the slot just consumed
          const uint4* p = Wf + (size_t)(t + s + 4) * 1024 + voff;
          bc[0] = p[0]; bc[1] = p[64]; bc[2] = p[128]; bc[3] = p[192];
        }
      }
    }
    // ---- expert epilogue: bias + gelu + gate-weighted accumulate
    {
      const int brow = wn * 64 + ln;
      float gv[2][4];
#pragma unroll
      for (int i = 0; i < 2; ++i)
#pragma unroll
        for (int r = 0; r < 4; ++r)
          gv[i][r] = gate_t[e * 65 + wm * 32 + i * 16 + quad * 4 + r];
#pragma unroll
      for (int j = 0; j < 4; ++j) {
        float bias = bf2f(be_h[e * BN + brow + j * 16]);
#pragma unroll
        for (int i = 0; i < 2; ++i)
#pragma unroll
          for (int r = 0; r < 4; ++r) {
            float hh = acc[i][j][r] + bias;
            oacc[i][j][r] = fmaf(gv[i][r], gelu_f(hh), oacc[i][j][r]);
            acc[i][j][r] = 0.f;
          }
      }
    }
  }

  // ---- store (each out element owned by exactly one block)
#pragma unroll
  for (int i = 0; i < 2; ++i)
#pragma unroll
    for (int r = 0; r < 4; ++r) {
      int row = m0 + wm * 32 + i * 16 + quad * 4 + r;
      float* orow = out + (size_t)row * NO + n0 + wn * 64 + ln;
      orow[0]  = oacc[i][0][r];
      orow[16] = oacc[i][1][r];
      orow[32] = oacc[i][2][r];
      orow[48] = oacc[i][3][r];
    }
}

extern "C" void kernel_launch(void* const* d_in, const int* in_sizes, int n_in,
                              void* d_out, int out_size, void* d_ws, size_t ws_size,
                              hipStream_t stream) {
  const float* x  = (const float*)d_in[0];
  const float* We = (const float*)d_in[1];
  const float* be = (const float*)d_in[2];
  const float* Wg = (const float*)d_in[3];
  const float* bg = (const float*)d_in[4];
  float* out = (float*)d_out;
  unsigned short* Wf  = (unsigned short*)d_ws;                                      // 2 MB bf16, fragment-ordered
  unsigned short* Wgt = (unsigned short*)((char*)d_ws + (size_t)NE * NO * KD * 2);  // 8 KB bf16 [E][D]

  moe_prep<<<257, 256, 0, stream>>>(We, Wf, Wg, Wgt);
  moe_main<<<512, 256, 0, stream>>>(x, (const uint4*)Wf, Wgt, be, bg, out);
}

// Round 5
// 123.134 us; speedup vs baseline: 1.4467x; 1.0372x over previous
//
#include <hip/hip_runtime.h>
#include <stdint.h>

#define KD 256
#define NO 256
#define NE 16
#define BM 64
#define BN 128
#define XROW 264        // X stage row stride (shorts): 256 + 8 pad
#define NFRAG 128       // NE * (KD/32) fragment-sets of K=32

typedef short bf16x8 __attribute__((ext_vector_type(8)));
typedef float f32x4 __attribute__((ext_vector_type(4)));

__device__ __forceinline__ unsigned short f2bf(float f) {
  uint32_t u = __float_as_uint(f);
  u += 0x7fffu + ((u >> 16) & 1u);   // RNE (finite inputs)
  return (unsigned short)(u >> 16);
}
__device__ __forceinline__ float bf2f(unsigned short h) {
  return __uint_as_float(((uint32_t)h) << 16);
}
// gelu(h) = h * sigmoid(1.59576912 h + 0.07135482 h^3)  (tanh form)
__device__ __forceinline__ float gelu_f(float h) {
  float z = h * fmaf(0.07135481627f, h * h, 1.5957691216f);
  return h * __builtin_amdgcn_rcpf(1.0f + __expf(-z));
}

// ---- prep: We[e][d][o] -> Wf fragment-ordered bf16; Wg[d][e] -> Wgt[e][d] bf16 ----
// Wf layout: [e][kc(0..7)][ob(0..15)][lane(0..63)][i(0..7)] bf16, element =
// We[e][ kc*32 + (lane>>4)*8 + i ][ ob*16 + (lane&15) ].  (UNCHANGED from R3 — proven)
__global__ void moe_prep(const float* __restrict__ We, unsigned short* __restrict__ Wf,
                         const float* __restrict__ Wg, unsigned short* __restrict__ Wgt)
{
  __shared__ float ts[256 * 17];  // [d][o] tile, padded
  const int tid = threadIdx.x;
  const int bid = blockIdx.x;
  if (bid < 256) {
    const int e = bid >> 4, ob = bid & 15;
    const float* src = We + (size_t)e * KD * NO + ob * 16;
    const int o = tid & 15, dg = tid >> 4;
#pragma unroll
    for (int p = 0; p < 16; ++p) {
      int d = p * 16 + dg;
      ts[d * 17 + o] = src[(size_t)d * NO + o];
    }
    __syncthreads();
    const int w = tid >> 6, l = tid & 63;
    const int q = l >> 4, ln = l & 15;
#pragma unroll
    for (int kk = 0; kk < 2; ++kk) {
      int kc = w + kk * 4;
      unsigned int pk[4];
#pragma unroll
      for (int h = 0; h < 4; ++h) {
        unsigned short lo = f2bf(ts[(kc * 32 + q * 8 + h * 2 + 0) * 17 + ln]);
        unsigned short hi = f2bf(ts[(kc * 32 + q * 8 + h * 2 + 1) * 17 + ln]);
        pk[h] = (unsigned int)lo | ((unsigned int)hi << 16);
      }
      uint4* dst = (uint4*)(Wf + ((((size_t)(e * 8 + kc) * 16 + ob) * 64) + l) * 8);
      *dst = make_uint4(pk[0], pk[1], pk[2], pk[3]);
    }
  } else {
    int d = tid;
    const float* wr = Wg + (size_t)d * NE;
#pragma unroll
    for (int e = 0; e < NE; ++e)
      Wgt[e * KD + d] = f2bf(wr[e]);
  }
}

// ---- main: 1m x 4n wave tiling (disjoint B streams), A FULLY register-resident ----
// No LDS reads inside the K-loop; A frags loaded once and never overwritten
// (avoids MFMA-source-overwrite hazard pattern suspected in R4).
__launch_bounds__(256, 2)
__global__ void moe_main(const float* __restrict__ x,
                         const uint4* __restrict__ Wf,
                         const unsigned short* __restrict__ Wgt,
                         const float* __restrict__ be,
                         const float* __restrict__ bg,
                         float* __restrict__ out)
{
  __shared__ __align__(16) unsigned short Xs[BM * XROW];  // 33792 B
  __shared__ float gate_t[NE * 65];                        // 4160 B
  __shared__ unsigned short be_h[NE * BN];                 // 4096 B

  const int tid = threadIdx.x;
  const int bid = blockIdx.x;
  const int half = bid & 1;
  const int n0 = half * BN;
  const int m0 = (bid >> 1) * BM;
  const int w = tid >> 6, lane = tid & 63;   // wave w owns cols w*32 .. w*32+31 (disjoint B)
  const int ln = lane & 15, quad = lane >> 4;

  // per-wave fragment offset (uint4 units); frag j at +j*64 (=1024 B imm)
  const int voff = (half * 8 + w * 2) * 64 + lane;

  // ---- stage X tile fp32 -> bf16
  {
    const float4* xg = (const float4*)x + (size_t)m0 * (KD / 4);
#pragma unroll
    for (int p = 0; p < 16; ++p) {
      int idx = p * 256 + tid;
      int r = idx >> 6, c = idx & 63;
      float4 v = xg[r * (KD / 4) + c];
      uint32_t lo = (uint32_t)f2bf(v.x) | ((uint32_t)f2bf(v.y) << 16);
      uint32_t hi = (uint32_t)f2bf(v.z) | ((uint32_t)f2bf(v.w) << 16);
      *(uint2*)&Xs[r * XROW + c * 4] = make_uint2(lo, hi);
    }
  }
  // ---- stage bias (bf16; |be|<=1/16 -> error ~1e-4)
#pragma unroll
  for (int p = 0; p < 8; ++p) {
    int idx = p * 256 + tid;
    int e = idx >> 7, c = idx & 127;
    be_h[e * BN + c] = f2bf(be[e * NO + n0 + c]);
  }
  __syncthreads();

  // ---- A fragments, FULL tile (64 rows x K=256): 32 frags = 128 VGPR, loaded ONCE
  bf16x8 a[4][8];
#pragma unroll
  for (int i = 0; i < 4; ++i)
#pragma unroll
    for (int kc = 0; kc < 8; ++kc)
      a[i][kc] = *(const bf16x8*)&Xs[(i * 16 + ln) * XROW + kc * 32 + quad * 8];

  // ---- ring fill: sets 0..3 (slot = t & 3), 8 outstanding 1KB loads
  uint4 b[4][2];
#pragma unroll
  for (int t = 0; t < 4; ++t) {
    const uint4* p = Wf + t * 1024 + voff;
    b[t][0] = p[0]; b[t][1] = p[64];
  }

  // ---- gate: wave w computes rows w*16..w*16+15 for all 16 experts (lane ln = expert)
  {
    f32x4 g = {0.f, 0.f, 0.f, 0.f};
#pragma unroll
    for (int kc = 0; kc < 8; ++kc) {
      bf16x8 af = *(const bf16x8*)&Xs[(w * 16 + ln) * XROW + kc * 32 + quad * 8];
      bf16x8 wb = *(const bf16x8*)(Wgt + (size_t)ln * KD + kc * 32 + quad * 8);
      g = __builtin_amdgcn_mfma_f32_16x16x32_bf16(af, wb, g, 0, 0, 0);
    }
    float bgl = bg[ln];
#pragma unroll
    for (int r = 0; r < 4; ++r) {
      float v = g[r] + bgl;
      float mx = v;
#pragma unroll
      for (int msk = 1; msk < 16; msk <<= 1)
        mx = fmaxf(mx, __shfl_xor(mx, msk, 64));
      float ev = __expf(v - mx);
      float s = ev;
#pragma unroll
      for (int msk = 1; msk < 16; msk <<= 1)
        s += __shfl_xor(s, msk, 64);
      gate_t[ln * 65 + w * 16 + quad * 4 + r] = ev * __builtin_amdgcn_rcpf(s);
    }
  }
  __syncthreads();  // gate_t visible; last barrier in the kernel

  f32x4 acc[4][2], oacc[4][2];
#pragma unroll
  for (int i = 0; i < 4; ++i)
#pragma unroll
    for (int j = 0; j < 2; ++j) {
      acc[i][j] = (f32x4){0.f, 0.f, 0.f, 0.f};
      oacc[i][j] = (f32x4){0.f, 0.f, 0.f, 0.f};
    }

  // running source pointer: set t at pw + t*1024 (uint4)
  const uint4* pw = Wf + 4 * 1024 + voff;   // next set to fetch = 4

#pragma unroll 1
  for (int e = 0; e < NE; ++e) {
#pragma unroll
    for (int kc = 0; kc < 8; ++kc) {
      const int t = e * 8 + kc;
      uint4* bc = b[t & 3];
#pragma unroll
      for (int i = 0; i < 4; ++i)
#pragma unroll
        for (int j = 0; j < 2; ++j)
          acc[i][j] = __builtin_amdgcn_mfma_f32_16x16x32_bf16(
              a[i][kc], *(const bf16x8*)&bc[j], acc[i][j], 0, 0, 0);
      if (t + 4 < NFRAG) {   // refill the slot just consumed with set t+4
        bc[0] = pw[0]; bc[1] = pw[64];
        pw += 1024;
      }
    }
    // ---- expert epilogue: bias + gelu + gate-weighted accumulate
    {
      float gv[4][4];
#pragma unroll
      for (int i = 0; i < 4; ++i)
#pragma unroll
        for (int r = 0; r < 4; ++r)
          gv[i][r] = gate_t[e * 65 + i * 16 + quad * 4 + r];
      float bb0 = bf2f(be_h[e * BN + w * 32 + ln]);
      float bb1 = bf2f(be_h[e * BN + w * 32 + 16 + ln]);
#pragma unroll
      for (int i = 0; i < 4; ++i)
#pragma unroll
        for (int j = 0; j < 2; ++j)
#pragma unroll
          for (int r = 0; r < 4; ++r) {
            float hh = acc[i][j][r] + (j ? bb1 : bb0);
            oacc[i][j][r] = fmaf(gv[i][r], gelu_f(hh), oacc[i][j][r]);
            acc[i][j][r] = 0.f;
          }
    }
  }

  // ---- store (each out element owned by exactly one wave)
#pragma unroll
  for (int i = 0; i < 4; ++i)
#pragma unroll
    for (int r = 0; r < 4; ++r) {
      int row = m0 + i * 16 + quad * 4 + r;
      float* orow = out + (size_t)row * NO + n0 + w * 32 + ln;
      orow[0]  = oacc[i][0][r];
      orow[16] = oacc[i][1][r];
    }
}

extern "C" void kernel_launch(void* const* d_in, const int* in_sizes, int n_in,
                              void* d_out, int out_size, void* d_ws, size_t ws_size,
                              hipStream_t stream) {
  const float* x  = (const float*)d_in[0];
  const float* We = (const float*)d_in[1];
  const float* be = (const float*)d_in[2];
  const float* Wg = (const float*)d_in[3];
  const float* bg = (const float*)d_in[4];
  float* out = (float*)d_out;
  unsigned short* Wf  = (unsigned short*)d_ws;                                      // 2 MB bf16, fragment-ordered
  unsigned short* Wgt = (unsigned short*)((char*)d_ws + (size_t)NE * NO * KD * 2);  // 8 KB bf16 [E][D]

  moe_prep<<<257, 256, 0, stream>>>(We, Wf, Wg, Wgt);
  moe_main<<<512, 256, 0, stream>>>(x, (const uint4*)Wf, Wgt, be, bg, out);
}